// Round 9
// baseline (728.063 us; speedup 1.0000x reference)
//
#include <hip/hip_runtime.h>
#include <hip/hip_bf16.h>
#include <math.h>

#define N_NODES 50000
#define N_EDGES 1600000
#define DIN 128
#define NH 4
#define D1 100
#define D2 20
#define NB 64
#define EPS_BN 1e-5f

// z1: [node][416] bf16 (832B rows; head seg at h*104, 100 used)
// z2: [node][128] bf16 (256B line-aligned; 80 used, col = h*20+j direct)
// h1: [node][400] bf16 unpadded (feeds MFMA GEMM2 directly)
// CSR: rank captured from hist's atomicAdd -> fill is an atomic-free scatter.
// Scores fused into gemm epilogues. Graph-pool fused into agg2 (atomic hg).

typedef unsigned int uint;
typedef unsigned short ushort;
typedef short short8v __attribute__((ext_vector_type(8)));
typedef float float4v __attribute__((ext_vector_type(4)));

#define Z1_ROWU 208  // uints per z1 row (416 bf16)
#define Z1_HU 52     // uints per z1 head segment (104 bf16)
#define Z2_ROWU 64   // uints per z2 row (128 bf16, 256B line-aligned)

__device__ __forceinline__ void bf16x2_unpack(uint p, float& lo, float& hi) {
  lo = __uint_as_float(p << 16);
  hi = __uint_as_float(p & 0xffff0000u);
}

__device__ __forceinline__ ushort f2bf(float f) {  // RNE, finite inputs
  uint u = __float_as_uint(f);
  return (ushort)((u + 0x7fffu + ((u >> 16) & 1u)) >> 16);
}

// ---------------------------------------------------------------------------
// Prep: B1t[h][j][k] bf16 (j padded to 128) from W1[h][k][j] fp32
// ---------------------------------------------------------------------------
__global__ void prep_b1t(const float* __restrict__ W1, ushort* __restrict__ B1t) {
  int o = blockIdx.x * 256 + threadIdx.x;  // 4*128*128 = 65536
  int h = o >> 14;
  int r = o & 16383;
  int j = r >> 7, k = r & 127;
  float v = (j < D1) ? W1[((size_t)h * DIN + k) * D1 + j] : 0.f;
  B1t[o] = f2bf(v);
}

// ---------------------------------------------------------------------------
// Prep: B2t[c][k] bf16, c = h*20+j (80 cols), K padded 400->416 with zeros
// ---------------------------------------------------------------------------
__global__ void prep_b2t(const float* __restrict__ W2, ushort* __restrict__ B2t) {
  int idx = blockIdx.x * 256 + threadIdx.x;  // 80*416 = 33280
  if (idx >= 80 * 416) return;
  int c = idx / 416, k = idx - c * 416;
  int h = c / D2, j = c - h * D2;
  float v = (k < NH * D1) ? W2[((size_t)h * (NH * D1) + k) * D2 + j] : 0.f;
  B2t[idx] = f2bf(v);
}

// ---------------------------------------------------------------------------
// GEMM1 via bf16 MFMA 16x16x32, BM=128, per-head blocks. A global->reg;
// B staged in LDS. Fused score epilogue.
// ---------------------------------------------------------------------------
__global__ __launch_bounds__(256) void gemm1_mfma(const float* __restrict__ feat,
                                                  const ushort* __restrict__ B1t,
                                                  const float* __restrict__ a1,
                                                  ushort* __restrict__ z1b,
                                                  float* __restrict__ ssrc,
                                                  float* __restrict__ sdst) {
  __shared__ __align__(16) short Bs[128 * 136];
  __shared__ float asd[2][104];
  const int row0 = blockIdx.x * 128;
  const int h = blockIdx.y;
  const int tid = threadIdx.x;
  {
    const uint* bsrc = reinterpret_cast<const uint*>(B1t + (size_t)h * 16384);
#pragma unroll
    for (int it = 0; it < 32; it++) {
      int idx = tid + it * 256;
      int j = idx >> 6, kk = idx & 63;
      *reinterpret_cast<uint*>(&Bs[j * 136 + kk * 2]) = bsrc[idx];
    }
  }
  if (tid < 208) {
    int which = tid >= 104;
    int cl = which ? tid - 104 : tid;
    asd[which][cl] = (cl < D1) ? a1[h * 2 * D1 + which * D1 + cl] : 0.f;
  }
  const int wv = tid >> 6, lane = tid & 63;
  const int m = lane & 15, q = lane >> 4;
  short8v a[2][4];
#pragma unroll
  for (int mt = 0; mt < 2; mt++) {
    int row = row0 + wv * 32 + mt * 16 + m;
    bool ok = row < N_NODES;
    const float* fr = feat + (size_t)(ok ? row : 0) * DIN;
#pragma unroll
    for (int kq = 0; kq < 4; kq++) {
      short8v s = (short8v){0, 0, 0, 0, 0, 0, 0, 0};
      if (ok) {
        float4 v0 = *reinterpret_cast<const float4*>(fr + kq * 32 + q * 8);
        float4 v1 = *reinterpret_cast<const float4*>(fr + kq * 32 + q * 8 + 4);
        s[0] = (short)f2bf(v0.x); s[1] = (short)f2bf(v0.y);
        s[2] = (short)f2bf(v0.z); s[3] = (short)f2bf(v0.w);
        s[4] = (short)f2bf(v1.x); s[5] = (short)f2bf(v1.y);
        s[6] = (short)f2bf(v1.z); s[7] = (short)f2bf(v1.w);
      }
      a[mt][kq] = s;
    }
  }
  __syncthreads();
  float4v acc[2][8];
#pragma unroll
  for (int mt = 0; mt < 2; mt++)
#pragma unroll
    for (int t = 0; t < 8; t++) acc[mt][t] = (float4v){0.f, 0.f, 0.f, 0.f};
#pragma unroll
  for (int kq = 0; kq < 4; kq++) {
#pragma unroll
    for (int t = 0; t < 8; t++) {
      short8v b = *reinterpret_cast<const short8v*>(&Bs[(t * 16 + m) * 136 + kq * 32 + q * 8]);
      acc[0][t] = __builtin_amdgcn_mfma_f32_16x16x32_bf16(a[0][kq], b, acc[0][t], 0, 0, 0);
      acc[1][t] = __builtin_amdgcn_mfma_f32_16x16x32_bf16(a[1][kq], b, acc[1][t], 0, 0, 0);
    }
  }
  // z1 write
#pragma unroll
  for (int mt = 0; mt < 2; mt++) {
#pragma unroll
    for (int t = 0; t < 8; t++) {
      int cl = t * 16 + m;
      if (cl < 104) {
#pragma unroll
        for (int reg = 0; reg < 4; reg++) {
          int row = row0 + wv * 32 + mt * 16 + q * 4 + reg;
          if (row < N_NODES)
            z1b[(size_t)row * 416 + h * 104 + cl] = (cl < D1) ? f2bf(acc[mt][t][reg]) : (ushort)0;
        }
      }
    }
  }
  // fused scores (cols >= 100 have asd = 0 and acc = 0)
  float aws[8], awd[8];
#pragma unroll
  for (int t = 0; t < 8; t++) {
    aws[t] = asd[0][t * 16 + m];
    awd[t] = asd[1][t * 16 + m];
  }
  float s1[2][4], s2v[2][4];
#pragma unroll
  for (int mt = 0; mt < 2; mt++)
#pragma unroll
    for (int reg = 0; reg < 4; reg++) {
      float p1 = 0.f, p2 = 0.f;
#pragma unroll
      for (int t = 0; t < 8; t++) {
        p1 += acc[mt][t][reg] * aws[t];
        p2 += acc[mt][t][reg] * awd[t];
      }
      s1[mt][reg] = p1;
      s2v[mt][reg] = p2;
    }
#pragma unroll
  for (int mt = 0; mt < 2; mt++)
#pragma unroll
    for (int reg = 0; reg < 4; reg++) {
#pragma unroll
      for (int off = 8; off >= 1; off >>= 1) {
        s1[mt][reg] += __shfl_xor(s1[mt][reg], off);
        s2v[mt][reg] += __shfl_xor(s2v[mt][reg], off);
      }
    }
  if (m == 0) {
#pragma unroll
    for (int mt = 0; mt < 2; mt++)
#pragma unroll
      for (int reg = 0; reg < 4; reg++) {
        int row = row0 + wv * 32 + mt * 16 + q * 4 + reg;
        if (row < N_NODES) ssrc[h * N_NODES + row] = s1[mt][reg];
      }
  } else if (m == 1) {
#pragma unroll
    for (int mt = 0; mt < 2; mt++)
#pragma unroll
      for (int reg = 0; reg < 4; reg++) {
        int row = row0 + wv * 32 + mt * 16 + q * 4 + reg;
        if (row < N_NODES) sdst[h * N_NODES + row] = s2v[mt][reg];
      }
  }
}

// ---------------------------------------------------------------------------
// GEMM2 via bf16 MFMA, 13-chunk LDS staging (3.3KB -> high occupancy).
// Fused scores for all 4 heads (masked LDS weight tables).
// ---------------------------------------------------------------------------
__global__ __launch_bounds__(256) void gemm2_mfma(const ushort* __restrict__ h1b,
                                                  const ushort* __restrict__ B2t,
                                                  const float* __restrict__ a2,
                                                  ushort* __restrict__ z2b,
                                                  float* __restrict__ ssrc,
                                                  float* __restrict__ sdst) {
  __shared__ __align__(16) short As[64 * 40];
  __shared__ __align__(16) short Bs[80 * 40];
  __shared__ float awcol[2][4][80];
  const int row0 = blockIdx.x * 64;
  const int tid = threadIdx.x;
  const int wv = tid >> 6, lane = tid & 63;
  const int m = lane & 15, q = lane >> 4;
  const uint* au = reinterpret_cast<const uint*>(h1b);
  const uint* bu = reinterpret_cast<const uint*>(B2t);
  uint* asu = reinterpret_cast<uint*>(As);
  uint* bsu = reinterpret_cast<uint*>(Bs);
  for (int i = tid; i < 640; i += 256) {
    int sc = i / 320;
    int r = i - sc * 320;
    int hh = r / 80, col = r - hh * 80;
    int ch = col / 20;
    awcol[sc][hh][col] = (ch == hh) ? a2[hh * 2 * D2 + sc * D2 + (col - 20 * hh)] : 0.f;
  }
  float4v acc[5];
#pragma unroll
  for (int t = 0; t < 5; t++) acc[t] = (float4v){0.f, 0.f, 0.f, 0.f};
  for (int ch = 0; ch < 13; ch++) {
    int k0u = ch * 16;
    {
      int idx = tid;
#pragma unroll
      for (int it = 0; it < 4; it++, idx += 256) {
        int r = idx >> 4, ku = idx & 15;
        int row = row0 + r;
        uint v = 0;
        if (row < N_NODES && (k0u + ku) < 200) v = au[(size_t)row * 200 + k0u + ku];
        asu[r * 20 + ku] = v;
      }
      idx = tid;
#pragma unroll
      for (int it = 0; it < 5; it++, idx += 256) {
        int c = idx >> 4, ku = idx & 15;
        bsu[c * 20 + ku] = bu[(size_t)c * 208 + k0u + ku];
      }
    }
    __syncthreads();
    short8v a = *reinterpret_cast<const short8v*>(&As[(wv * 16 + m) * 40 + q * 8]);
#pragma unroll
    for (int t = 0; t < 5; t++) {
      short8v b = *reinterpret_cast<const short8v*>(&Bs[(t * 16 + m) * 40 + q * 8]);
      acc[t] = __builtin_amdgcn_mfma_f32_16x16x32_bf16(a, b, acc[t], 0, 0, 0);
    }
    __syncthreads();
  }
  // z2 write
#pragma unroll
  for (int t = 0; t < 5; t++) {
    int col = t * 16 + m;  // 0..79 packed col = h*20+j
#pragma unroll
    for (int reg = 0; reg < 4; reg++) {
      int r2 = row0 + wv * 16 + q * 4 + reg;
      if (r2 < N_NODES) z2b[(size_t)r2 * 128 + col] = f2bf(acc[t][reg]);
    }
  }
  // fused scores: per-head masked weights
  float w1v[4][5], w2v[4][5];
#pragma unroll
  for (int hh = 0; hh < 4; hh++)
#pragma unroll
    for (int t = 0; t < 5; t++) {
      w1v[hh][t] = awcol[0][hh][t * 16 + m];
      w2v[hh][t] = awcol[1][hh][t * 16 + m];
    }
  float ps[2][4][4];  // [score][head][reg]
#pragma unroll
  for (int hh = 0; hh < 4; hh++)
#pragma unroll
    for (int reg = 0; reg < 4; reg++) {
      float p1 = 0.f, p2 = 0.f;
#pragma unroll
      for (int t = 0; t < 5; t++) {
        p1 += acc[t][reg] * w1v[hh][t];
        p2 += acc[t][reg] * w2v[hh][t];
      }
      ps[0][hh][reg] = p1;
      ps[1][hh][reg] = p2;
    }
#pragma unroll
  for (int hh = 0; hh < 4; hh++)
#pragma unroll
    for (int reg = 0; reg < 4; reg++) {
#pragma unroll
      for (int off = 8; off >= 1; off >>= 1) {
        ps[0][hh][reg] += __shfl_xor(ps[0][hh][reg], off);
        ps[1][hh][reg] += __shfl_xor(ps[1][hh][reg], off);
      }
    }
#pragma unroll
  for (int hh = 0; hh < 4; hh++) {
    if (m == hh) {
#pragma unroll
      for (int reg = 0; reg < 4; reg++) {
        int r2 = row0 + wv * 16 + q * 4 + reg;
        if (r2 < N_NODES) ssrc[hh * N_NODES + r2] = ps[0][hh][reg];
      }
    }
    if (m == hh + 4) {
#pragma unroll
      for (int reg = 0; reg < 4; reg++) {
        int r2 = row0 + wv * 16 + q * 4 + reg;
        if (r2 < N_NODES) sdst[hh * N_NODES + r2] = ps[1][hh][reg];
      }
    }
  }
}

// ---------------------------------------------------------------------------
// CSR build: histogram (+rank capture), 3-kernel hierarchical scan,
// atomic-free scatter fill.
// ---------------------------------------------------------------------------
__global__ void hist_kernel(const int* __restrict__ dst, int* __restrict__ cnt,
                            int* __restrict__ rank) {
  int e = blockIdx.x * blockDim.x + threadIdx.x;
  if (e < N_EDGES) rank[e] = atomicAdd(&cnt[dst[e]], 1);
}

__global__ __launch_bounds__(512) void scan1_kernel(const int* __restrict__ cnt,
                                                    int* __restrict__ row_ptr,
                                                    int* __restrict__ btot, int n) {
  __shared__ int ws[8];
  int b = blockIdx.x, tid = threadIdx.x, lane = tid & 63, wv = tid >> 6;
  int i = b * 512 + tid;
  int v = (i < n) ? cnt[i] : 0;
  int orig = v;
  for (int off = 1; off < 64; off <<= 1) {
    int t = __shfl_up(v, off);
    if (lane >= off) v += t;
  }
  if (lane == 63) ws[wv] = v;
  __syncthreads();
  int wo = 0;
  for (int j = 0; j < wv; j++) wo += ws[j];
  if (i < n) row_ptr[i] = wo + v - orig;
  if (tid == 511) btot[b] = wo + v;
}

__global__ __launch_bounds__(128) void scan2_kernel(int* __restrict__ btot,
                                                    int* __restrict__ row_ptr_n, int nb) {
  __shared__ int ws2[2];
  int tid = threadIdx.x, lane = tid & 63, wv = tid >> 6;
  int v = (tid < nb) ? btot[tid] : 0;
  int orig = v;
  for (int off = 1; off < 64; off <<= 1) {
    int t = __shfl_up(v, off);
    if (lane >= off) v += t;
  }
  if (lane == 63) ws2[wv] = v;
  __syncthreads();
  int wo = (wv == 1) ? ws2[0] : 0;
  if (tid < nb) btot[tid] = wo + v - orig;
  if (tid == nb - 1) *row_ptr_n = wo + v;
}

__global__ __launch_bounds__(512) void scan3_kernel(int* __restrict__ row_ptr,
                                                    const int* __restrict__ btot, int n) {
  int i = blockIdx.x * 512 + threadIdx.x;
  if (i < n) row_ptr[i] += btot[blockIdx.x];
}

__global__ void fill_kernel(const int* __restrict__ src, const int* __restrict__ dst,
                            const int* __restrict__ row_ptr, const int* __restrict__ rank,
                            int* __restrict__ csr_src) {
  int e = blockIdx.x * blockDim.x + threadIdx.x;
  if (e < N_EDGES) csr_src[row_ptr[dst[e]] + rank[e]] = src[e];
}

// ---------------------------------------------------------------------------
// Graph node counts (gid sorted): wave-level pre-reduction.
// ---------------------------------------------------------------------------
__global__ __launch_bounds__(256) void gcnt_kernel(const int* __restrict__ gid,
                                                   int* __restrict__ gcnt) {
  int wave = threadIdx.x >> 6, lane = threadIdx.x & 63;
  int n = (blockIdx.x * 4 + wave) * 64 + lane;
  bool valid = n < N_NODES;
  int g = gid[valid ? n : (N_NODES - 1)];
  int g0 = __shfl(g, 0), g63 = __shfl(g, 63);
  unsigned long long mask = __ballot(valid);
  if (g0 == g63) {
    if (lane == 0) atomicAdd(&gcnt[g0], (int)__popcll(mask));
  } else if (valid) {
    atomicAdd(&gcnt[g], 1);
  }
}

// ---------------------------------------------------------------------------
// GAT layer 1 aggregation, weights fused. Block = dst, wave = head.
// Per 128-edge chunk: lane-parallel exp into per-wave LDS row (den inline),
// then 8-deep z-gather loop (dword, 50 lanes) with LDS weight broadcasts.
// ---------------------------------------------------------------------------
__global__ __launch_bounds__(256) void agg1_kernel(const ushort* __restrict__ z,
                                                   const float* __restrict__ ssrc,
                                                   const float* __restrict__ sdst,
                                                   const int* __restrict__ row_ptr,
                                                   const int* __restrict__ csr_src,
                                                   ushort* __restrict__ h1b) {
  __shared__ float lw[NH][128];
  const int d = blockIdx.x;
  const int h = threadIdx.x >> 6, lane = threadIdx.x & 63;
  const int beg = row_ptr[d], end = row_ptr[d + 1];
  const int deg = end - beg;
  uint* h1u = reinterpret_cast<uint*>(h1b);
  const size_t ou = (size_t)d * 200 + h * 50 + lane;
  const bool act = lane < D1 / 2;  // 50 lanes
  if (deg == 0) {
    if (act) h1u[ou] = 0u;
    return;
  }
  const int hN = h * N_NODES;
  const float sd = sdst[hN + d];
  const uint* zb = reinterpret_cast<const uint*>(z);
  const int hco = h * Z1_HU + lane;  // used by act lanes only
  float den = 0.f;
  float aE0 = 0.f, aE1 = 0.f, aE2 = 0.f, aE3 = 0.f;
  float aO0 = 0.f, aO1 = 0.f, aO2 = 0.f, aO3 = 0.f;
  for (int c0 = 0; c0 < deg; c0 += 128) {
    const int cn = min(128, deg - c0);
    const int cb = beg + c0;
    for (int i = lane; i < cn; i += 64) {
      int s = csr_src[cb + i];
      float e = ssrc[hN + s] + sd;
      e = fmaxf(e, 0.01f * e);
      float x = __expf(e);
      lw[h][i] = x;
      den += x;
    }
    if (act) {
      int j = 0;
      for (; j + 8 <= cn; j += 8) {
        int s0 = csr_src[cb + j + 0], s1 = csr_src[cb + j + 1];
        int s2 = csr_src[cb + j + 2], s3 = csr_src[cb + j + 3];
        int s4 = csr_src[cb + j + 4], s5 = csr_src[cb + j + 5];
        int s6 = csr_src[cb + j + 6], s7 = csr_src[cb + j + 7];
        float x0 = lw[h][j + 0], x1 = lw[h][j + 1];
        float x2 = lw[h][j + 2], x3 = lw[h][j + 3];
        float x4 = lw[h][j + 4], x5 = lw[h][j + 5];
        float x6 = lw[h][j + 6], x7 = lw[h][j + 7];
        uint p0 = zb[(size_t)s0 * Z1_ROWU + hco];
        uint p1 = zb[(size_t)s1 * Z1_ROWU + hco];
        uint p2 = zb[(size_t)s2 * Z1_ROWU + hco];
        uint p3 = zb[(size_t)s3 * Z1_ROWU + hco];
        uint p4 = zb[(size_t)s4 * Z1_ROWU + hco];
        uint p5 = zb[(size_t)s5 * Z1_ROWU + hco];
        uint p6 = zb[(size_t)s6 * Z1_ROWU + hco];
        uint p7 = zb[(size_t)s7 * Z1_ROWU + hco];
        float lo, hi;
        bf16x2_unpack(p0, lo, hi); aE0 += x0 * lo; aO0 += x0 * hi;
        bf16x2_unpack(p1, lo, hi); aE1 += x1 * lo; aO1 += x1 * hi;
        bf16x2_unpack(p2, lo, hi); aE2 += x2 * lo; aO2 += x2 * hi;
        bf16x2_unpack(p3, lo, hi); aE3 += x3 * lo; aO3 += x3 * hi;
        bf16x2_unpack(p4, lo, hi); aE0 += x4 * lo; aO0 += x4 * hi;
        bf16x2_unpack(p5, lo, hi); aE1 += x5 * lo; aO1 += x5 * hi;
        bf16x2_unpack(p6, lo, hi); aE2 += x6 * lo; aO2 += x6 * hi;
        bf16x2_unpack(p7, lo, hi); aE3 += x7 * lo; aO3 += x7 * hi;
      }
      for (; j < cn; j++) {
        int s = csr_src[cb + j];
        float x = lw[h][j];
        uint p = zb[(size_t)s * Z1_ROWU + hco];
        float lo, hi;
        bf16x2_unpack(p, lo, hi);
        aE0 += x * lo;
        aO0 += x * hi;
      }
    }
  }
#pragma unroll
  for (int off = 32; off > 0; off >>= 1) den += __shfl_xor(den, off);
  if (!act) return;
  float inv = 1.0f / den;
  float vE = ((aE0 + aE1) + (aE2 + aE3)) * inv;
  float vO = ((aO0 + aO1) + (aO2 + aO3)) * inv;
  vE = vE > 0.f ? vE : 0.f;
  vO = vO > 0.f ? vO : 0.f;
  h1u[ou] = (uint)f2bf(vE) | ((uint)f2bf(vO) << 16);
}

// ---------------------------------------------------------------------------
// GAT layer 2 aggregation + head-mean + relu + graph-pool (atomic hg).
// Block = dst, 4 waves each take 8-edge chunks (all heads). Phase A: lanes
// 0..31 (lane = e*4+h) compute exp weights -> wave-local LDS. Phase B: lanes
// 0..39 gather the FULL 160B z2 row. Cross-wave reduce; epilogue atomicAdds
// the relu'd node row into hg[gid[d]]. No h2 buffer.
// ---------------------------------------------------------------------------
__global__ __launch_bounds__(256) void agg2_kernel(const ushort* __restrict__ z,
                                                   const float* __restrict__ ssrc,
                                                   const float* __restrict__ sdst,
                                                   const int* __restrict__ row_ptr,
                                                   const int* __restrict__ csr_src,
                                                   const int* __restrict__ gid,
                                                   float* __restrict__ hg) {
  __shared__ float xw[4][8][4];      // [wave][e][h] exp weights (0 for pad slots)
  __shared__ int sw[4][8];           // [wave][e] src (clamped for pad slots)
  __shared__ float accb[4][40][2];   // [wave][uint-slot][lo/hi]
  __shared__ float denb[4][4];       // [wave][h]
  const int d = blockIdx.x;
  const int wv = threadIdx.x >> 6, lane = threadIdx.x & 63;
  const int beg = row_ptr[d];
  const int deg = row_ptr[d + 1] - beg;
  if (deg == 0) return;  // contributes 0 to the graph sum
  const int eh_h = lane & 3, eh_e = lane >> 2;  // phase-A mapping (lanes 0..31)
  const int hq = lane / 10;                     // phase-B head (lanes 0..39)
  const uint* zu = reinterpret_cast<const uint*>(z);
  float sd = 0.f;
  if (lane < 32) sd = sdst[eh_h * N_NODES + d];
  float den = 0.f;
  float acc0 = 0.f, acc1 = 0.f;
  for (int c0 = wv * 8; c0 < deg; c0 += 32) {
    const int cn = min(8, deg - c0);
    const int cb = beg + c0;
    // phase A
    if (lane < 32) {
      int ee = (eh_e < cn) ? eh_e : 0;
      int s = csr_src[cb + ee];
      float e = ssrc[eh_h * N_NODES + s] + sd;
      e = fmaxf(e, 0.01f * e);
      float x = (eh_e < cn) ? __expf(e) : 0.f;
      den += x;
      xw[wv][eh_e][eh_h] = x;
      if (eh_h == 0) sw[wv][eh_e] = s;
    }
    // phase B (same wave: LDS visible after compiler-inserted lgkmcnt)
    if (lane < 40) {
#pragma unroll
      for (int e = 0; e < 8; e++) {
        int se = sw[wv][e];
        float xx = xw[wv][e][hq];
        uint p = zu[(size_t)se * Z2_ROWU + lane];
        float lo, hi;
        bf16x2_unpack(p, lo, hi);
        acc0 += xx * lo;
        acc1 += xx * hi;
      }
    }
  }
  // den: reduce over e-lanes (masks 4,8,16 stay within each head class)
  den += __shfl_xor(den, 4);
  den += __shfl_xor(den, 8);
  den += __shfl_xor(den, 16);
  if (lane < 4) denb[wv][lane] = den;
  if (lane < 40) {
    accb[wv][lane][0] = acc0;
    accb[wv][lane][1] = acc1;
  }
  __syncthreads();
  if (threadIdx.x < 10) {
    int j = threadIdx.x;  // feature pair within head
    int g = gid[d];
    float vE = 0.f, vO = 0.f;
#pragma unroll
    for (int h = 0; h < 4; h++) {
      float dn = denb[0][h] + denb[1][h] + denb[2][h] + denb[3][h];
      float invd = 1.0f / dn;
      int sl = h * 10 + j;
      float lo = accb[0][sl][0] + accb[1][sl][0] + accb[2][sl][0] + accb[3][sl][0];
      float hi = accb[0][sl][1] + accb[1][sl][1] + accb[2][sl][1] + accb[3][sl][1];
      vE += lo * invd;
      vO += hi * invd;
    }
    vE *= 0.25f;
    vO *= 0.25f;
    vE = vE > 0.f ? vE : 0.f;
    vO = vO > 0.f ? vO : 0.f;
    atomicAdd(&hg[g * D2 + 2 * j], vE);
    atomicAdd(&hg[g * D2 + 2 * j + 1], vO);
  }
}

// ---------------------------------------------------------------------------
// Readout MLP + BatchNorm + final projection in one block.
// ---------------------------------------------------------------------------
__global__ __launch_bounds__(256) void head_kernel(const float* __restrict__ hg,
                                                   const int* __restrict__ gcnt,
                                                   const float* __restrict__ Wf1,
                                                   const float* __restrict__ bf1,
                                                   const float* __restrict__ Wf2,
                                                   const float* __restrict__ bf2,
                                                   const float* __restrict__ Wf3,
                                                   const float* __restrict__ bf3,
                                                   const float* __restrict__ gamma,
                                                   const float* __restrict__ beta,
                                                   float* __restrict__ out) {
  __shared__ float X[NB][D2];
  __shared__ float T1[NB][128];
  __shared__ float T2[NB][32];
  __shared__ float scale_s[32], shift_s[32];
  int tid = threadIdx.x;
  for (int i = tid; i < NB * D2; i += 256) {
    int r = i / D2, c = i % D2;
    X[r][c] = hg[i] / (float)gcnt[r];
  }
  __syncthreads();
  for (int i = tid; i < NB * 128; i += 256) {
    int r = i >> 7, c = i & 127;
    float s = bf1[c];
#pragma unroll
    for (int k = 0; k < D2; k++) s += X[r][k] * Wf1[k * 128 + c];
    T1[r][c] = s > 0.f ? s : 0.f;
  }
  __syncthreads();
  for (int i = tid; i < NB * 32; i += 256) {
    int r = i >> 5, c = i & 31;
    float s = bf2[c];
#pragma unroll
    for (int k = 0; k < 128; k++) s += T1[r][k] * Wf2[k * 32 + c];
    T2[r][c] = s;
  }
  __syncthreads();
  if (tid < 32) {
    float mu = 0.f;
    for (int r = 0; r < NB; r++) mu += T2[r][tid];
    mu *= (1.f / NB);
    float var = 0.f;
    for (int r = 0; r < NB; r++) {
      float dv = T2[r][tid] - mu;
      var += dv * dv;
    }
    var *= (1.f / NB);
    float sc = gamma[tid] * rsqrtf(var + EPS_BN);
    scale_s[tid] = sc;
    shift_s[tid] = beta[tid] - mu * sc;
  }
  __syncthreads();
  if (tid < NB) {
    float s = bf3[0];
#pragma unroll
    for (int c = 0; c < 32; c++) {
      float y = scale_s[c] * T2[tid][c] + shift_s[c];
      y = y > 0.f ? y : 0.f;
      s += y * Wf3[c];
    }
    out[tid] = s;
  }
}

// ---------------------------------------------------------------------------

extern "C" void kernel_launch(void* const* d_in, const int* in_sizes, int n_in,
                              void* d_out, int out_size, void* d_ws, size_t ws_size,
                              hipStream_t stream) {
  const float* feat = (const float*)d_in[0];
  const int* src = (const int*)d_in[1];
  const int* dst = (const int*)d_in[2];
  const int* gid = (const int*)d_in[3];
  const float* W1 = (const float*)d_in[4];
  const float* a1 = (const float*)d_in[5];
  const float* W2 = (const float*)d_in[6];
  const float* a2 = (const float*)d_in[7];
  const float* Wf1 = (const float*)d_in[8];
  const float* bf1 = (const float*)d_in[9];
  const float* Wf2 = (const float*)d_in[10];
  const float* bf2 = (const float*)d_in[11];
  const float* Wf3 = (const float*)d_in[12];
  const float* bf3 = (const float*)d_in[13];
  const float* gamma2 = (const float*)d_in[14];
  const float* beta2 = (const float*)d_in[15];
  float* outp = (float*)d_out;

  char* p = (char*)d_ws;
  auto alloc = [&](size_t bytes) {
    void* q = (void*)p;
    p += (bytes + 255) & ~(size_t)255;
    return q;
  };
  ushort* z1b = (ushort*)alloc((size_t)N_NODES * 416 * 2);       // 41.6 MB
  ushort* z2b = (ushort*)alloc((size_t)N_NODES * 128 * 2);       // 12.8 MB (256B rows)
  ushort* h1b = (ushort*)alloc((size_t)N_NODES * NH * D1 * 2);   // 40 MB
  float* ssrc = (float*)alloc((size_t)NH * N_NODES * 4);
  float* sdst = (float*)alloc((size_t)NH * N_NODES * 4);
  int* cnt = (int*)alloc((size_t)N_NODES * 4);
  int* row_ptr = (int*)alloc((size_t)(N_NODES + 1) * 4);
  int* rank = (int*)alloc((size_t)N_EDGES * 4);                  // 6.4 MB
  int* csr = (int*)alloc((size_t)N_EDGES * 4);
  int* btot = (int*)alloc((size_t)128 * 4);
  ushort* B1t = (ushort*)alloc((size_t)NH * 128 * 128 * 2);      // 128 KB
  ushort* B2t = (ushort*)alloc((size_t)80 * 416 * 2);            // 66.6 KB
  float* hg = (float*)alloc((size_t)NB * D2 * 4);
  int* gcnt = (int*)alloc((size_t)NB * 4);

  const int rows128 = (N_NODES + 127) / 128;     // 391
  const int rows64 = (N_NODES + 63) / 64;        // 782
  const int eblk = (N_EDGES + 255) / 256;        // 6250
  const int nblk = (N_NODES + 255) / 256;        // 196
  const int sblk = (N_NODES + 511) / 512;        // 98

  // CSR build (rank captured in hist; fill is atomic-free)
  hipMemsetAsync(cnt, 0, (size_t)N_NODES * 4, stream);
  hipMemsetAsync(hg, 0, (size_t)NB * D2 * 4, stream);
  hipMemsetAsync(gcnt, 0, (size_t)NB * 4, stream);
  hist_kernel<<<eblk, 256, 0, stream>>>(dst, cnt, rank);
  scan1_kernel<<<sblk, 512, 0, stream>>>(cnt, row_ptr, btot, N_NODES);
  scan2_kernel<<<1, 128, 0, stream>>>(btot, row_ptr + N_NODES, sblk);
  scan3_kernel<<<sblk, 512, 0, stream>>>(row_ptr, btot, N_NODES);
  fill_kernel<<<eblk, 256, 0, stream>>>(src, dst, row_ptr, rank, csr);

  // Weight prep + graph counts (independent)
  prep_b1t<<<256, 256, 0, stream>>>(W1, B1t);
  prep_b2t<<<130, 256, 0, stream>>>(W2, B2t);
  gcnt_kernel<<<nblk, 256, 0, stream>>>(gid, gcnt);

  // Layer 1 (scores fused into gemm epilogue)
  gemm1_mfma<<<dim3(rows128, NH), 256, 0, stream>>>(feat, B1t, a1, z1b, ssrc, sdst);
  agg1_kernel<<<N_NODES, 256, 0, stream>>>(z1b, ssrc, sdst, row_ptr, csr, h1b);

  // Layer 2 (scores fused; graph-pool fused via atomics)
  gemm2_mfma<<<rows64, 256, 0, stream>>>(h1b, B2t, a2, z2b, ssrc, sdst);
  agg2_kernel<<<N_NODES, 256, 0, stream>>>(z2b, ssrc, sdst, row_ptr, csr, gid, hg);

  // Readout
  head_kernel<<<1, 256, 0, stream>>>(hg, gcnt, Wf1, bf1, Wf2, bf2, Wf3, bf3,
                                     gamma2, beta2, outp);
}

// Round 11
// 613.893 us; speedup vs baseline: 1.1860x; 1.1860x over previous
//
#include <hip/hip_runtime.h>
#include <hip/hip_bf16.h>
#include <math.h>

#define N_NODES 50000
#define N_EDGES 1600000
#define DIN 128
#define NH 4
#define D1 100
#define D2 20
#define NB 64
#define EPS_BN 1e-5f

// z1: [node][416] bf16 (832B rows; head seg at h*104, 100 used)
// z2: [node][128] bf16 (256B line-aligned; 80 used, col = h*20+j direct)
// h1: [node][400] bf16 unpadded (feeds MFMA GEMM2 directly)
// CSR: rank captured from hist's atomicAdd -> fill is an atomic-free scatter.
// Scores fused into gemm epilogues (fp32 acc) — no scores kernels.
// fp8 z1 REFUTED (R10): absmax 3.42e-3 > 3.34e-3 threshold. bf16 is minimum.

typedef unsigned int uint;
typedef unsigned short ushort;
typedef short short8v __attribute__((ext_vector_type(8)));
typedef float float4v __attribute__((ext_vector_type(4)));

#define Z1_ROWU 208  // uints per z1 row (416 bf16)
#define Z1_HU 52     // uints per z1 head segment (104 bf16)
#define Z2_ROWU 64   // uints per z2 row (128 bf16, 256B line-aligned)

__device__ __forceinline__ void bf16x2_unpack(uint p, float& lo, float& hi) {
  lo = __uint_as_float(p << 16);
  hi = __uint_as_float(p & 0xffff0000u);
}

__device__ __forceinline__ ushort f2bf(float f) {  // RNE, finite inputs
  uint u = __float_as_uint(f);
  return (ushort)((u + 0x7fffu + ((u >> 16) & 1u)) >> 16);
}

// ---------------------------------------------------------------------------
// Prep: B1t[h][j][k] bf16 (j padded to 128) from W1[h][k][j] fp32
// ---------------------------------------------------------------------------
__global__ void prep_b1t(const float* __restrict__ W1, ushort* __restrict__ B1t) {
  int o = blockIdx.x * 256 + threadIdx.x;  // 4*128*128 = 65536
  int h = o >> 14;
  int r = o & 16383;
  int j = r >> 7, k = r & 127;
  float v = (j < D1) ? W1[((size_t)h * DIN + k) * D1 + j] : 0.f;
  B1t[o] = f2bf(v);
}

// ---------------------------------------------------------------------------
// Prep: B2t[c][k] bf16, c = h*20+j (80 cols), K padded 400->416 with zeros
// ---------------------------------------------------------------------------
__global__ void prep_b2t(const float* __restrict__ W2, ushort* __restrict__ B2t) {
  int idx = blockIdx.x * 256 + threadIdx.x;  // 80*416 = 33280
  if (idx >= 80 * 416) return;
  int c = idx / 416, k = idx - c * 416;
  int h = c / D2, j = c - h * D2;
  float v = (k < NH * D1) ? W2[((size_t)h * (NH * D1) + k) * D2 + j] : 0.f;
  B2t[idx] = f2bf(v);
}

// ---------------------------------------------------------------------------
// GEMM1 via bf16 MFMA 16x16x32, BM=128, per-head blocks. A global->reg;
// B staged in LDS. Fused score epilogue: s1/s2 from fp32 acc, 16-lane
// butterfly, m==0/m==1 lanes write ssrc/sdst.
// ---------------------------------------------------------------------------
__global__ __launch_bounds__(256) void gemm1_mfma(const float* __restrict__ feat,
                                                  const ushort* __restrict__ B1t,
                                                  const float* __restrict__ a1,
                                                  ushort* __restrict__ z1b,
                                                  float* __restrict__ ssrc,
                                                  float* __restrict__ sdst) {
  __shared__ __align__(16) short Bs[128 * 136];
  __shared__ float asd[2][104];
  const int row0 = blockIdx.x * 128;
  const int h = blockIdx.y;
  const int tid = threadIdx.x;
  {
    const uint* bsrc = reinterpret_cast<const uint*>(B1t + (size_t)h * 16384);
#pragma unroll
    for (int it = 0; it < 32; it++) {
      int idx = tid + it * 256;
      int j = idx >> 6, kk = idx & 63;
      *reinterpret_cast<uint*>(&Bs[j * 136 + kk * 2]) = bsrc[idx];
    }
  }
  if (tid < 208) {
    int which = tid >= 104;
    int cl = which ? tid - 104 : tid;
    asd[which][cl] = (cl < D1) ? a1[h * 2 * D1 + which * D1 + cl] : 0.f;
  }
  const int wv = tid >> 6, lane = tid & 63;
  const int m = lane & 15, q = lane >> 4;
  short8v a[2][4];
#pragma unroll
  for (int mt = 0; mt < 2; mt++) {
    int row = row0 + wv * 32 + mt * 16 + m;
    bool ok = row < N_NODES;
    const float* fr = feat + (size_t)(ok ? row : 0) * DIN;
#pragma unroll
    for (int kq = 0; kq < 4; kq++) {
      short8v s = (short8v){0, 0, 0, 0, 0, 0, 0, 0};
      if (ok) {
        float4 v0 = *reinterpret_cast<const float4*>(fr + kq * 32 + q * 8);
        float4 v1 = *reinterpret_cast<const float4*>(fr + kq * 32 + q * 8 + 4);
        s[0] = (short)f2bf(v0.x); s[1] = (short)f2bf(v0.y);
        s[2] = (short)f2bf(v0.z); s[3] = (short)f2bf(v0.w);
        s[4] = (short)f2bf(v1.x); s[5] = (short)f2bf(v1.y);
        s[6] = (short)f2bf(v1.z); s[7] = (short)f2bf(v1.w);
      }
      a[mt][kq] = s;
    }
  }
  __syncthreads();
  float4v acc[2][8];
#pragma unroll
  for (int mt = 0; mt < 2; mt++)
#pragma unroll
    for (int t = 0; t < 8; t++) acc[mt][t] = (float4v){0.f, 0.f, 0.f, 0.f};
#pragma unroll
  for (int kq = 0; kq < 4; kq++) {
#pragma unroll
    for (int t = 0; t < 8; t++) {
      short8v b = *reinterpret_cast<const short8v*>(&Bs[(t * 16 + m) * 136 + kq * 32 + q * 8]);
      acc[0][t] = __builtin_amdgcn_mfma_f32_16x16x32_bf16(a[0][kq], b, acc[0][t], 0, 0, 0);
      acc[1][t] = __builtin_amdgcn_mfma_f32_16x16x32_bf16(a[1][kq], b, acc[1][t], 0, 0, 0);
    }
  }
  // z1 write
#pragma unroll
  for (int mt = 0; mt < 2; mt++) {
#pragma unroll
    for (int t = 0; t < 8; t++) {
      int cl = t * 16 + m;
      if (cl < 104) {
#pragma unroll
        for (int reg = 0; reg < 4; reg++) {
          int row = row0 + wv * 32 + mt * 16 + q * 4 + reg;
          if (row < N_NODES)
            z1b[(size_t)row * 416 + h * 104 + cl] = (cl < D1) ? f2bf(acc[mt][t][reg]) : (ushort)0;
        }
      }
    }
  }
  // fused scores (cols >= 100 have asd = 0 and acc = 0)
  float aws[8], awd[8];
#pragma unroll
  for (int t = 0; t < 8; t++) {
    aws[t] = asd[0][t * 16 + m];
    awd[t] = asd[1][t * 16 + m];
  }
  float s1[2][4], s2v[2][4];
#pragma unroll
  for (int mt = 0; mt < 2; mt++)
#pragma unroll
    for (int reg = 0; reg < 4; reg++) {
      float p1 = 0.f, p2 = 0.f;
#pragma unroll
      for (int t = 0; t < 8; t++) {
        p1 += acc[mt][t][reg] * aws[t];
        p2 += acc[mt][t][reg] * awd[t];
      }
      s1[mt][reg] = p1;
      s2v[mt][reg] = p2;
    }
#pragma unroll
  for (int mt = 0; mt < 2; mt++)
#pragma unroll
    for (int reg = 0; reg < 4; reg++) {
#pragma unroll
      for (int off = 8; off >= 1; off >>= 1) {
        s1[mt][reg] += __shfl_xor(s1[mt][reg], off);
        s2v[mt][reg] += __shfl_xor(s2v[mt][reg], off);
      }
    }
  if (m == 0) {
#pragma unroll
    for (int mt = 0; mt < 2; mt++)
#pragma unroll
      for (int reg = 0; reg < 4; reg++) {
        int row = row0 + wv * 32 + mt * 16 + q * 4 + reg;
        if (row < N_NODES) ssrc[h * N_NODES + row] = s1[mt][reg];
      }
  } else if (m == 1) {
#pragma unroll
    for (int mt = 0; mt < 2; mt++)
#pragma unroll
      for (int reg = 0; reg < 4; reg++) {
        int row = row0 + wv * 32 + mt * 16 + q * 4 + reg;
        if (row < N_NODES) sdst[h * N_NODES + row] = s2v[mt][reg];
      }
  }
}

// ---------------------------------------------------------------------------
// GEMM2 via bf16 MFMA, 13-chunk LDS staging (3.3KB -> high occupancy).
// Fused scores for all 4 heads (masked LDS weight tables).
// ---------------------------------------------------------------------------
__global__ __launch_bounds__(256) void gemm2_mfma(const ushort* __restrict__ h1b,
                                                  const ushort* __restrict__ B2t,
                                                  const float* __restrict__ a2,
                                                  ushort* __restrict__ z2b,
                                                  float* __restrict__ ssrc,
                                                  float* __restrict__ sdst) {
  __shared__ __align__(16) short As[64 * 40];
  __shared__ __align__(16) short Bs[80 * 40];
  __shared__ float awcol[2][4][80];
  const int row0 = blockIdx.x * 64;
  const int tid = threadIdx.x;
  const int wv = tid >> 6, lane = tid & 63;
  const int m = lane & 15, q = lane >> 4;
  const uint* au = reinterpret_cast<const uint*>(h1b);
  const uint* bu = reinterpret_cast<const uint*>(B2t);
  uint* asu = reinterpret_cast<uint*>(As);
  uint* bsu = reinterpret_cast<uint*>(Bs);
  for (int i = tid; i < 640; i += 256) {
    int sc = i / 320;
    int r = i - sc * 320;
    int hh = r / 80, col = r - hh * 80;
    int ch = col / 20;
    awcol[sc][hh][col] = (ch == hh) ? a2[hh * 2 * D2 + sc * D2 + (col - 20 * hh)] : 0.f;
  }
  float4v acc[5];
#pragma unroll
  for (int t = 0; t < 5; t++) acc[t] = (float4v){0.f, 0.f, 0.f, 0.f};
  for (int ch = 0; ch < 13; ch++) {
    int k0u = ch * 16;
    {
      int idx = tid;
#pragma unroll
      for (int it = 0; it < 4; it++, idx += 256) {
        int r = idx >> 4, ku = idx & 15;
        int row = row0 + r;
        uint v = 0;
        if (row < N_NODES && (k0u + ku) < 200) v = au[(size_t)row * 200 + k0u + ku];
        asu[r * 20 + ku] = v;
      }
      idx = tid;
#pragma unroll
      for (int it = 0; it < 5; it++, idx += 256) {
        int c = idx >> 4, ku = idx & 15;
        bsu[c * 20 + ku] = bu[(size_t)c * 208 + k0u + ku];
      }
    }
    __syncthreads();
    short8v a = *reinterpret_cast<const short8v*>(&As[(wv * 16 + m) * 40 + q * 8]);
#pragma unroll
    for (int t = 0; t < 5; t++) {
      short8v b = *reinterpret_cast<const short8v*>(&Bs[(t * 16 + m) * 40 + q * 8]);
      acc[t] = __builtin_amdgcn_mfma_f32_16x16x32_bf16(a, b, acc[t], 0, 0, 0);
    }
    __syncthreads();
  }
  // z2 write
#pragma unroll
  for (int t = 0; t < 5; t++) {
    int col = t * 16 + m;  // 0..79 packed col = h*20+j
#pragma unroll
    for (int reg = 0; reg < 4; reg++) {
      int r2 = row0 + wv * 16 + q * 4 + reg;
      if (r2 < N_NODES) z2b[(size_t)r2 * 128 + col] = f2bf(acc[t][reg]);
    }
  }
  // fused scores: per-head masked weights
  float w1v[4][5], w2v[4][5];
#pragma unroll
  for (int hh = 0; hh < 4; hh++)
#pragma unroll
    for (int t = 0; t < 5; t++) {
      w1v[hh][t] = awcol[0][hh][t * 16 + m];
      w2v[hh][t] = awcol[1][hh][t * 16 + m];
    }
  float ps[2][4][4];  // [score][head][reg]
#pragma unroll
  for (int hh = 0; hh < 4; hh++)
#pragma unroll
    for (int reg = 0; reg < 4; reg++) {
      float p1 = 0.f, p2 = 0.f;
#pragma unroll
      for (int t = 0; t < 5; t++) {
        p1 += acc[t][reg] * w1v[hh][t];
        p2 += acc[t][reg] * w2v[hh][t];
      }
      ps[0][hh][reg] = p1;
      ps[1][hh][reg] = p2;
    }
#pragma unroll
  for (int hh = 0; hh < 4; hh++)
#pragma unroll
    for (int reg = 0; reg < 4; reg++) {
#pragma unroll
      for (int off = 8; off >= 1; off >>= 1) {
        ps[0][hh][reg] += __shfl_xor(ps[0][hh][reg], off);
        ps[1][hh][reg] += __shfl_xor(ps[1][hh][reg], off);
      }
    }
#pragma unroll
  for (int hh = 0; hh < 4; hh++) {
    if (m == hh) {
#pragma unroll
      for (int reg = 0; reg < 4; reg++) {
        int r2 = row0 + wv * 16 + q * 4 + reg;
        if (r2 < N_NODES) ssrc[hh * N_NODES + r2] = ps[0][hh][reg];
      }
    }
    if (m == hh + 4) {
#pragma unroll
      for (int reg = 0; reg < 4; reg++) {
        int r2 = row0 + wv * 16 + q * 4 + reg;
        if (r2 < N_NODES) sdst[hh * N_NODES + r2] = ps[1][hh][reg];
      }
    }
  }
}

// ---------------------------------------------------------------------------
// CSR build: histogram (+rank capture), 3-kernel hierarchical scan,
// atomic-free scatter fill.
// ---------------------------------------------------------------------------
__global__ void hist_kernel(const int* __restrict__ dst, int* __restrict__ cnt,
                            int* __restrict__ rank) {
  int e = blockIdx.x * blockDim.x + threadIdx.x;
  if (e < N_EDGES) rank[e] = atomicAdd(&cnt[dst[e]], 1);
}

__global__ __launch_bounds__(512) void scan1_kernel(const int* __restrict__ cnt,
                                                    int* __restrict__ row_ptr,
                                                    int* __restrict__ btot, int n) {
  __shared__ int ws[8];
  int b = blockIdx.x, tid = threadIdx.x, lane = tid & 63, wv = tid >> 6;
  int i = b * 512 + tid;
  int v = (i < n) ? cnt[i] : 0;
  int orig = v;
  for (int off = 1; off < 64; off <<= 1) {
    int t = __shfl_up(v, off);
    if (lane >= off) v += t;
  }
  if (lane == 63) ws[wv] = v;
  __syncthreads();
  int wo = 0;
  for (int j = 0; j < wv; j++) wo += ws[j];
  if (i < n) row_ptr[i] = wo + v - orig;
  if (tid == 511) btot[b] = wo + v;
}

__global__ __launch_bounds__(128) void scan2_kernel(int* __restrict__ btot,
                                                    int* __restrict__ row_ptr_n, int nb) {
  __shared__ int ws2[2];
  int tid = threadIdx.x, lane = tid & 63, wv = tid >> 6;
  int v = (tid < nb) ? btot[tid] : 0;
  int orig = v;
  for (int off = 1; off < 64; off <<= 1) {
    int t = __shfl_up(v, off);
    if (lane >= off) v += t;
  }
  if (lane == 63) ws2[wv] = v;
  __syncthreads();
  int wo = (wv == 1) ? ws2[0] : 0;
  if (tid < nb) btot[tid] = wo + v - orig;
  if (tid == nb - 1) *row_ptr_n = wo + v;
}

__global__ __launch_bounds__(512) void scan3_kernel(int* __restrict__ row_ptr,
                                                    const int* __restrict__ btot, int n) {
  int i = blockIdx.x * 512 + threadIdx.x;
  if (i < n) row_ptr[i] += btot[blockIdx.x];
}

__global__ void fill_kernel(const int* __restrict__ src, const int* __restrict__ dst,
                            const int* __restrict__ row_ptr, const int* __restrict__ rank,
                            int* __restrict__ csr_src) {
  int e = blockIdx.x * blockDim.x + threadIdx.x;
  if (e < N_EDGES) csr_src[row_ptr[dst[e]] + rank[e]] = src[e];
}

// ---------------------------------------------------------------------------
// GAT layer 1 aggregation, weights fused. Block = dst, wave = head.
// Per 128-edge chunk: lane-parallel exp into per-wave LDS row (den inline),
// then 8-deep z-gather loop (dword, 50 lanes) with LDS weight broadcasts.
// ---------------------------------------------------------------------------
__global__ __launch_bounds__(256) void agg1_kernel(const ushort* __restrict__ z,
                                                   const float* __restrict__ ssrc,
                                                   const float* __restrict__ sdst,
                                                   const int* __restrict__ row_ptr,
                                                   const int* __restrict__ csr_src,
                                                   ushort* __restrict__ h1b) {
  __shared__ float lw[NH][128];
  const int d = blockIdx.x;
  const int h = threadIdx.x >> 6, lane = threadIdx.x & 63;
  const int beg = row_ptr[d], end = row_ptr[d + 1];
  const int deg = end - beg;
  uint* h1u = reinterpret_cast<uint*>(h1b);
  const size_t ou = (size_t)d * 200 + h * 50 + lane;
  const bool act = lane < D1 / 2;  // 50 lanes
  if (deg == 0) {
    if (act) h1u[ou] = 0u;
    return;
  }
  const int hN = h * N_NODES;
  const float sd = sdst[hN + d];
  const uint* zb = reinterpret_cast<const uint*>(z);
  const int hco = h * Z1_HU + lane;  // used by act lanes only
  float den = 0.f;
  float aE0 = 0.f, aE1 = 0.f, aE2 = 0.f, aE3 = 0.f;
  float aO0 = 0.f, aO1 = 0.f, aO2 = 0.f, aO3 = 0.f;
  for (int c0 = 0; c0 < deg; c0 += 128) {
    const int cn = min(128, deg - c0);
    const int cb = beg + c0;
    for (int i = lane; i < cn; i += 64) {
      int s = csr_src[cb + i];
      float e = ssrc[hN + s] + sd;
      e = fmaxf(e, 0.01f * e);
      float x = __expf(e);
      lw[h][i] = x;
      den += x;
    }
    if (act) {
      int j = 0;
      for (; j + 8 <= cn; j += 8) {
        int s0 = csr_src[cb + j + 0], s1 = csr_src[cb + j + 1];
        int s2 = csr_src[cb + j + 2], s3 = csr_src[cb + j + 3];
        int s4 = csr_src[cb + j + 4], s5 = csr_src[cb + j + 5];
        int s6 = csr_src[cb + j + 6], s7 = csr_src[cb + j + 7];
        float x0 = lw[h][j + 0], x1 = lw[h][j + 1];
        float x2 = lw[h][j + 2], x3 = lw[h][j + 3];
        float x4 = lw[h][j + 4], x5 = lw[h][j + 5];
        float x6 = lw[h][j + 6], x7 = lw[h][j + 7];
        uint p0 = zb[(size_t)s0 * Z1_ROWU + hco];
        uint p1 = zb[(size_t)s1 * Z1_ROWU + hco];
        uint p2 = zb[(size_t)s2 * Z1_ROWU + hco];
        uint p3 = zb[(size_t)s3 * Z1_ROWU + hco];
        uint p4 = zb[(size_t)s4 * Z1_ROWU + hco];
        uint p5 = zb[(size_t)s5 * Z1_ROWU + hco];
        uint p6 = zb[(size_t)s6 * Z1_ROWU + hco];
        uint p7 = zb[(size_t)s7 * Z1_ROWU + hco];
        float lo, hi;
        bf16x2_unpack(p0, lo, hi); aE0 += x0 * lo; aO0 += x0 * hi;
        bf16x2_unpack(p1, lo, hi); aE1 += x1 * lo; aO1 += x1 * hi;
        bf16x2_unpack(p2, lo, hi); aE2 += x2 * lo; aO2 += x2 * hi;
        bf16x2_unpack(p3, lo, hi); aE3 += x3 * lo; aO3 += x3 * hi;
        bf16x2_unpack(p4, lo, hi); aE0 += x4 * lo; aO0 += x4 * hi;
        bf16x2_unpack(p5, lo, hi); aE1 += x5 * lo; aO1 += x5 * hi;
        bf16x2_unpack(p6, lo, hi); aE2 += x6 * lo; aO2 += x6 * hi;
        bf16x2_unpack(p7, lo, hi); aE3 += x7 * lo; aO3 += x7 * hi;
      }
      for (; j < cn; j++) {
        int s = csr_src[cb + j];
        float x = lw[h][j];
        uint p = zb[(size_t)s * Z1_ROWU + hco];
        float lo, hi;
        bf16x2_unpack(p, lo, hi);
        aE0 += x * lo;
        aO0 += x * hi;
      }
    }
  }
#pragma unroll
  for (int off = 32; off > 0; off >>= 1) den += __shfl_xor(den, off);
  if (!act) return;
  float inv = 1.0f / den;
  float vE = ((aE0 + aE1) + (aE2 + aE3)) * inv;
  float vO = ((aO0 + aO1) + (aO2 + aO3)) * inv;
  vE = vE > 0.f ? vE : 0.f;
  vO = vO > 0.f ? vO : 0.f;
  h1u[ou] = (uint)f2bf(vE) | ((uint)f2bf(vO) << 16);
}

// ---------------------------------------------------------------------------
// GAT layer 2 aggregation + head-mean + relu. Block = dst, 4 waves each take
// 8-edge chunks (all heads). Phase A: lanes 0..31 compute exp weights -> LDS.
// Phase B: lanes 0..39 gather the full 160B z2 row. Cross-wave reduce in LDS.
// ---------------------------------------------------------------------------
__global__ __launch_bounds__(256) void agg2_kernel(const ushort* __restrict__ z,
                                                   const float* __restrict__ ssrc,
                                                   const float* __restrict__ sdst,
                                                   const int* __restrict__ row_ptr,
                                                   const int* __restrict__ csr_src,
                                                   float* __restrict__ h2) {
  __shared__ float xw[4][8][4];      // [wave][e][h] exp weights (0 for pad slots)
  __shared__ int sw[4][8];           // [wave][e] src (clamped for pad slots)
  __shared__ float accb[4][40][2];   // [wave][uint-slot][lo/hi]
  __shared__ float denb[4][4];       // [wave][h]
  const int d = blockIdx.x;
  const int wv = threadIdx.x >> 6, lane = threadIdx.x & 63;
  const int beg = row_ptr[d];
  const int deg = row_ptr[d + 1] - beg;
  if (deg == 0) {
    if (threadIdx.x < D2) h2[(size_t)d * D2 + threadIdx.x] = 0.f;
    return;
  }
  const int eh_h = lane & 3, eh_e = lane >> 2;  // phase-A mapping (lanes 0..31)
  const int hq = lane / 10;                     // phase-B head (lanes 0..39)
  const uint* zu = reinterpret_cast<const uint*>(z);
  float sd = 0.f;
  if (lane < 32) sd = sdst[eh_h * N_NODES + d];
  float den = 0.f;
  float acc0 = 0.f, acc1 = 0.f;
  for (int c0 = wv * 8; c0 < deg; c0 += 32) {
    const int cn = min(8, deg - c0);
    const int cb = beg + c0;
    // phase A
    if (lane < 32) {
      int ee = (eh_e < cn) ? eh_e : 0;
      int s = csr_src[cb + ee];
      float e = ssrc[eh_h * N_NODES + s] + sd;
      e = fmaxf(e, 0.01f * e);
      float x = (eh_e < cn) ? __expf(e) : 0.f;
      den += x;
      xw[wv][eh_e][eh_h] = x;
      if (eh_h == 0) sw[wv][eh_e] = s;
    }
    // phase B (same wave: LDS visible after compiler-inserted lgkmcnt)
    if (lane < 40) {
#pragma unroll
      for (int e = 0; e < 8; e++) {
        int se = sw[wv][e];
        float xx = xw[wv][e][hq];
        uint p = zu[(size_t)se * Z2_ROWU + lane];
        float lo, hi;
        bf16x2_unpack(p, lo, hi);
        acc0 += xx * lo;
        acc1 += xx * hi;
      }
    }
  }
  // den: reduce over e-lanes (masks 4,8,16 stay within each head class)
  den += __shfl_xor(den, 4);
  den += __shfl_xor(den, 8);
  den += __shfl_xor(den, 16);
  if (lane < 4) denb[wv][lane] = den;
  if (lane < 40) {
    accb[wv][lane][0] = acc0;
    accb[wv][lane][1] = acc1;
  }
  __syncthreads();
  if (threadIdx.x < 10) {
    int j = threadIdx.x;  // feature pair within head
    float vE = 0.f, vO = 0.f;
#pragma unroll
    for (int h = 0; h < 4; h++) {
      float dn = denb[0][h] + denb[1][h] + denb[2][h] + denb[3][h];
      float invd = 1.0f / dn;
      int sl = h * 10 + j;
      float lo = accb[0][sl][0] + accb[1][sl][0] + accb[2][sl][0] + accb[3][sl][0];
      float hi = accb[0][sl][1] + accb[1][sl][1] + accb[2][sl][1] + accb[3][sl][1];
      vE += lo * invd;
      vO += hi * invd;
    }
    vE *= 0.25f;
    vO *= 0.25f;
    h2[(size_t)d * D2 + 2 * j] = vE > 0.f ? vE : 0.f;
    h2[(size_t)d * D2 + 2 * j + 1] = vO > 0.f ? vO : 0.f;
  }
}

// ---------------------------------------------------------------------------
// Graph mean-pool: wave-level pre-reduction (graph_id is sorted).
// ---------------------------------------------------------------------------
__global__ __launch_bounds__(256) void pool_kernel(const float* __restrict__ h2,
                                                   const int* __restrict__ gid,
                                                   float* __restrict__ hg,
                                                   int* __restrict__ gcnt) {
  int wave = threadIdx.x >> 6, lane = threadIdx.x & 63;
  int n = (blockIdx.x * 4 + wave) * 64 + lane;
  bool valid = n < N_NODES;
  int g = gid[valid ? n : (N_NODES - 1)];
  int g0 = __shfl(g, 0), g63 = __shfl(g, 63);
  unsigned long long mask = __ballot(valid);
  if (g0 == g63) {
    if (lane == 0) atomicAdd(&gcnt[g0], (int)__popcll(mask));
#pragma unroll
    for (int c = 0; c < D2; c++) {
      float v = valid ? h2[(size_t)n * D2 + c] : 0.f;
#pragma unroll
      for (int off = 32; off > 0; off >>= 1) v += __shfl_xor(v, off);
      if (lane == 0) atomicAdd(&hg[g0 * D2 + c], v);
    }
  } else if (valid) {
    atomicAdd(&gcnt[g], 1);
    for (int c = 0; c < D2; c++) atomicAdd(&hg[g * D2 + c], h2[(size_t)n * D2 + c]);
  }
}

// ---------------------------------------------------------------------------
// Readout MLP + BatchNorm + final projection in one block.
// ---------------------------------------------------------------------------
__global__ __launch_bounds__(256) void head_kernel(const float* __restrict__ hg,
                                                   const int* __restrict__ gcnt,
                                                   const float* __restrict__ Wf1,
                                                   const float* __restrict__ bf1,
                                                   const float* __restrict__ Wf2,
                                                   const float* __restrict__ bf2,
                                                   const float* __restrict__ Wf3,
                                                   const float* __restrict__ bf3,
                                                   const float* __restrict__ gamma,
                                                   const float* __restrict__ beta,
                                                   float* __restrict__ out) {
  __shared__ float X[NB][D2];
  __shared__ float T1[NB][128];
  __shared__ float T2[NB][32];
  __shared__ float scale_s[32], shift_s[32];
  int tid = threadIdx.x;
  for (int i = tid; i < NB * D2; i += 256) {
    int r = i / D2, c = i % D2;
    X[r][c] = hg[i] / (float)gcnt[r];
  }
  __syncthreads();
  for (int i = tid; i < NB * 128; i += 256) {
    int r = i >> 7, c = i & 127;
    float s = bf1[c];
#pragma unroll
    for (int k = 0; k < D2; k++) s += X[r][k] * Wf1[k * 128 + c];
    T1[r][c] = s > 0.f ? s : 0.f;
  }
  __syncthreads();
  for (int i = tid; i < NB * 32; i += 256) {
    int r = i >> 5, c = i & 31;
    float s = bf2[c];
#pragma unroll
    for (int k = 0; k < 128; k++) s += T1[r][k] * Wf2[k * 32 + c];
    T2[r][c] = s;
  }
  __syncthreads();
  if (tid < 32) {
    float mu = 0.f;
    for (int r = 0; r < NB; r++) mu += T2[r][tid];
    mu *= (1.f / NB);
    float var = 0.f;
    for (int r = 0; r < NB; r++) {
      float dv = T2[r][tid] - mu;
      var += dv * dv;
    }
    var *= (1.f / NB);
    float sc = gamma[tid] * rsqrtf(var + EPS_BN);
    scale_s[tid] = sc;
    shift_s[tid] = beta[tid] - mu * sc;
  }
  __syncthreads();
  if (tid < NB) {
    float s = bf3[0];
#pragma unroll
    for (int c = 0; c < 32; c++) {
      float y = scale_s[c] * T2[tid][c] + shift_s[c];
      y = y > 0.f ? y : 0.f;
      s += y * Wf3[c];
    }
    out[tid] = s;
  }
}

// ---------------------------------------------------------------------------

extern "C" void kernel_launch(void* const* d_in, const int* in_sizes, int n_in,
                              void* d_out, int out_size, void* d_ws, size_t ws_size,
                              hipStream_t stream) {
  const float* feat = (const float*)d_in[0];
  const int* src = (const int*)d_in[1];
  const int* dst = (const int*)d_in[2];
  const int* gid = (const int*)d_in[3];
  const float* W1 = (const float*)d_in[4];
  const float* a1 = (const float*)d_in[5];
  const float* W2 = (const float*)d_in[6];
  const float* a2 = (const float*)d_in[7];
  const float* Wf1 = (const float*)d_in[8];
  const float* bf1 = (const float*)d_in[9];
  const float* Wf2 = (const float*)d_in[10];
  const float* bf2 = (const float*)d_in[11];
  const float* Wf3 = (const float*)d_in[12];
  const float* bf3 = (const float*)d_in[13];
  const float* gamma2 = (const float*)d_in[14];
  const float* beta2 = (const float*)d_in[15];
  float* outp = (float*)d_out;

  char* p = (char*)d_ws;
  auto alloc = [&](size_t bytes) {
    void* q = (void*)p;
    p += (bytes + 255) & ~(size_t)255;
    return q;
  };
  ushort* z1b = (ushort*)alloc((size_t)N_NODES * 416 * 2);       // 41.6 MB
  ushort* z2b = (ushort*)alloc((size_t)N_NODES * 128 * 2);       // 12.8 MB (256B rows)
  ushort* h1b = (ushort*)alloc((size_t)N_NODES * NH * D1 * 2);   // 40 MB
  float* h2 = (float*)alloc((size_t)N_NODES * D2 * 4);           // 4 MB
  float* ssrc = (float*)alloc((size_t)NH * N_NODES * 4);
  float* sdst = (float*)alloc((size_t)NH * N_NODES * 4);
  int* cnt = (int*)alloc((size_t)N_NODES * 4);
  int* row_ptr = (int*)alloc((size_t)(N_NODES + 1) * 4);
  int* rank = (int*)alloc((size_t)N_EDGES * 4);                  // 6.4 MB
  int* csr = (int*)alloc((size_t)N_EDGES * 4);
  int* btot = (int*)alloc((size_t)128 * 4);
  ushort* B1t = (ushort*)alloc((size_t)NH * 128 * 128 * 2);      // 128 KB
  ushort* B2t = (ushort*)alloc((size_t)80 * 416 * 2);            // 66.6 KB
  float* hg = (float*)alloc((size_t)NB * D2 * 4);
  int* gcnt = (int*)alloc((size_t)NB * 4);

  const int rows128 = (N_NODES + 127) / 128;     // 391
  const int rows64 = (N_NODES + 63) / 64;        // 782
  const int eblk = (N_EDGES + 255) / 256;        // 6250
  const int nblk = (N_NODES + 255) / 256;        // 196
  const int sblk = (N_NODES + 511) / 512;        // 98

  // CSR build (rank captured in hist; fill is atomic-free)
  hipMemsetAsync(cnt, 0, (size_t)N_NODES * 4, stream);
  hist_kernel<<<eblk, 256, 0, stream>>>(dst, cnt, rank);
  scan1_kernel<<<sblk, 512, 0, stream>>>(cnt, row_ptr, btot, N_NODES);
  scan2_kernel<<<1, 128, 0, stream>>>(btot, row_ptr + N_NODES, sblk);
  scan3_kernel<<<sblk, 512, 0, stream>>>(row_ptr, btot, N_NODES);
  fill_kernel<<<eblk, 256, 0, stream>>>(src, dst, row_ptr, rank, csr);

  // Weight prep (independent)
  prep_b1t<<<256, 256, 0, stream>>>(W1, B1t);
  prep_b2t<<<130, 256, 0, stream>>>(W2, B2t);

  // Layer 1 (scores fused into gemm epilogue)
  gemm1_mfma<<<dim3(rows128, NH), 256, 0, stream>>>(feat, B1t, a1, z1b, ssrc, sdst);
  agg1_kernel<<<N_NODES, 256, 0, stream>>>(z1b, ssrc, sdst, row_ptr, csr, h1b);

  // Layer 2 (scores fused into gemm epilogue)
  gemm2_mfma<<<rows64, 256, 0, stream>>>(h1b, B2t, a2, z2b, ssrc, sdst);
  agg2_kernel<<<N_NODES, 256, 0, stream>>>(z2b, ssrc, sdst, row_ptr, csr, h2);

  // Readout
  hipMemsetAsync(hg, 0, (size_t)NB * D2 * 4, stream);
  hipMemsetAsync(gcnt, 0, (size_t)NB * 4, stream);
  pool_kernel<<<nblk, 256, 0, stream>>>(h2, gid, hg, gcnt);
  head_kernel<<<1, 256, 0, stream>>>(hg, gcnt, Wf1, bf1, Wf2, bf2, Wf3, bf3,
                                     gamma2, beta2, outp);
}